// Round 1
// baseline (1201.849 us; speedup 1.0000x reference)
//
#include <hip/hip_runtime.h>
#include <hip/hip_bf16.h>
#include <cstdio>

// Problem constants (S6HistoryCompressor)
#define S_LEN 2048
#define BATCH 16
#define D_INP 1024
#define H_DIM 2048
#define SC    (S_LEN / 2)       // compressed length (step=2, rows 1,3,...,2047)
#define BH    (BATCH * H_DIM)   // 32768 independent recurrences
#define NC    16                // scan chunks
#define CS    (S_LEN / NC)      // 128 steps per chunk

typedef __bf16 b16;
typedef __bf16 b16x8 __attribute__((ext_vector_type(8)));
typedef __bf16 b16x4 __attribute__((ext_vector_type(4)));
typedef float  f32x4 __attribute__((ext_vector_type(4)));

// XOR swizzle for LDS tile [128 rows][32 bf16 cols], 16B granules.
// (r,k8) -> element offset. Gives 2-way (free) bank aliasing on frag reads.
__device__ __forceinline__ int sw_off(int r, int k8) {
  return r * 32 + ((k8 ^ ((r >> 1) & 3)) << 3);
}

// ---------------------------------------------------------------------------
// Conversions
// ---------------------------------------------------------------------------
__global__ void cvt_x_kernel(const float* __restrict__ in, b16* __restrict__ out, int n4) {
  int i = blockIdx.x * 256 + threadIdx.x;
  if (i >= n4) return;
  float4 v = ((const float4*)in)[i];
  b16x4 o = {(b16)v.x, (b16)v.y, (b16)v.z, (b16)v.w};
  ((b16x4*)out)[i] = o;
}

// Build Wdu = [W_delta ; W_in + W_B] (bf16), plus bf16 copies of W_C, W_comp.
__global__ void prep_w_kernel(const float* __restrict__ Wd, const float* __restrict__ Win,
                              const float* __restrict__ WB, const float* __restrict__ Wc,
                              const float* __restrict__ Wcp,
                              b16* __restrict__ Wdu, b16* __restrict__ Wcb,
                              b16* __restrict__ Wcpb) {
  const int HD4 = (H_DIM * D_INP) / 4;
  int i = blockIdx.x * 256 + threadIdx.x;
  if (i >= HD4) return;
  float4 a = ((const float4*)Wd)[i];
  float4 b = ((const float4*)Win)[i];
  float4 c = ((const float4*)WB)[i];
  float4 d = ((const float4*)Wc)[i];
  float4 e = ((const float4*)Wcp)[i];
  ((b16x4*)Wdu)[i] = {(b16)a.x, (b16)a.y, (b16)a.z, (b16)a.w};
  ((b16x4*)Wdu)[HD4 + i] = {(b16)(b.x + c.x), (b16)(b.y + c.y), (b16)(b.z + c.z), (b16)(b.w + c.w)};
  ((b16x4*)Wcb)[i] = {(b16)d.x, (b16)d.y, (b16)d.z, (b16)d.w};
  ((b16x4*)Wcpb)[i] = {(b16)e.x, (b16)e.y, (b16)e.z, (b16)e.w};
}

// ---------------------------------------------------------------------------
// GEMM: C[M,N] = A[M,K] (bf16 row-major) x W[N,K]^T (bf16 row-major, i.e. B^T)
// 128x128 block tile, 4 waves, each wave 64x64 via 4x4 grid of 16x16x32 MFMA.
// MODE 0: N=2*H. n<H: delta=softplus(acc+b_delta[n]) -> ob0; else u=acc+b_in -> ob1.
// MODE 1: A rows remapped to odd timesteps of x; out = acc * hsel -> ob0 (y_sel).
// MODE 2: out fp32 = acc + bias0[n] -> of (final output).
// ---------------------------------------------------------------------------
template <int MODE>
__global__ __launch_bounds__(256, 2) void gemm_bt(
    const b16* __restrict__ A, const b16* __restrict__ W, int K,
    const float* __restrict__ bias0, const float* __restrict__ bias1,
    const b16* __restrict__ hsel, b16* __restrict__ ob0, b16* __restrict__ ob1,
    float* __restrict__ of) {
  __shared__ b16 As[128 * 32];
  __shared__ b16 Bs[128 * 32];
  const int tid  = threadIdx.x;
  const int lane = tid & 63;
  const int wave = tid >> 6;
  const int wr = wave >> 1, wc = wave & 1;
  const int rs  = tid >> 2;   // staging row 0..63 (plus +64 second half)
  const int k8s = tid & 3;    // staging 16B granule within the 32-elem row
  const int m0 = blockIdx.y * 128;
  const int n0 = blockIdx.x * 128;
  const int lm = lane & 15;
  const int l8 = lane >> 4;

  f32x4 acc[4][4];
#pragma unroll
  for (int i = 0; i < 4; i++)
#pragma unroll
    for (int j = 0; j < 4; j++) acc[i][j] = (f32x4)0.f;

  for (int k0 = 0; k0 < K; k0 += 32) {
#pragma unroll
    for (int hh = 0; hh < 2; ++hh) {
      int rr = rs + hh * 64;
      long arow = m0 + rr;
      if (MODE == 1) arow = 2 * arow - (arow & 15) + 16;  // odd-timestep remap
      int4 va = *(const int4*)(A + arow * (long)K + k0 + k8s * 8);
      *(int4*)(As + sw_off(rr, k8s)) = va;
      int4 vb = *(const int4*)(W + (long)(n0 + rr) * K + k0 + k8s * 8);
      *(int4*)(Bs + sw_off(rr, k8s)) = vb;
    }
    __syncthreads();
    b16x8 af[4], bfr[4];
#pragma unroll
    for (int i = 0; i < 4; i++) af[i] = *(const b16x8*)(As + sw_off(wr * 64 + i * 16 + lm, l8));
#pragma unroll
    for (int j = 0; j < 4; j++) bfr[j] = *(const b16x8*)(Bs + sw_off(wc * 64 + j * 16 + lm, l8));
#pragma unroll
    for (int i = 0; i < 4; i++)
#pragma unroll
      for (int j = 0; j < 4; j++)
        acc[i][j] = __builtin_amdgcn_mfma_f32_16x16x32_bf16(af[i], bfr[j], acc[i][j], 0, 0, 0);
    __syncthreads();
  }

  // Epilogue. C/D layout: col = lane&15, row = (lane>>4)*4 + reg [m89/m91 verified].
#pragma unroll
  for (int i = 0; i < 4; i++) {
#pragma unroll
    for (int j = 0; j < 4; j++) {
      int n = n0 + wc * 64 + j * 16 + lm;
      int mb = m0 + wr * 64 + i * 16 + l8 * 4;
#pragma unroll
      for (int rg = 0; rg < 4; ++rg) {
        float v = acc[i][j][rg];
        long m = mb + rg;
        if (MODE == 0) {
          if (n < H_DIM) {
            float t = v + bias0[n];
            float sp = (t > 15.f) ? t : log1pf(expf(t));
            ob0[m * H_DIM + n] = (b16)sp;
          } else {
            ob1[m * H_DIM + (n - H_DIM)] = (b16)(v + bias1[n - H_DIM]);
          }
        } else if (MODE == 1) {
          float hv = (float)hsel[m * H_DIM + n];
          ob0[m * H_DIM + n] = (b16)(v * hv);
        } else {
          of[m * D_INP + n] = v + bias0[n];
        }
      }
    }
  }
}

// ---------------------------------------------------------------------------
// Chunked-scan recurrence: h_t = (1-d_t) h_{t-1} + d_t u_t  (elementwise in B*H)
// ---------------------------------------------------------------------------
__global__ void scan_a_kernel(const b16* __restrict__ dl, const b16* __restrict__ uu,
                              float* __restrict__ P, float* __restrict__ Q) {
  int g = blockIdx.x * 256 + threadIdx.x;  // [0, NC*BH)
  int c = g >> 15;                          // chunk
  int p = g & (BH - 1);                     // (b,h) flat
  const b16* dp = dl + (size_t)c * CS * BH + p;
  const b16* up = uu + (size_t)c * CS * BH + p;
  float h = 0.f, pr = 1.f;
#pragma unroll 4
  for (int s = 0; s < CS; ++s) {
    float d = (float)dp[(size_t)s * BH];
    float u = (float)up[(size_t)s * BH];
    float a = 1.f - d;
    h = a * h + d * u;
    pr *= a;
  }
  P[g] = pr;
  Q[g] = h;
}

__global__ void scan_b_kernel(const float* __restrict__ P, const float* __restrict__ Q,
                              float* __restrict__ Hs) {
  int p = blockIdx.x * 256 + threadIdx.x;  // [0, BH)
  float h = 0.f;
#pragma unroll
  for (int c = 0; c < NC; ++c) {
    Hs[c * BH + p] = h;
    h = P[c * BH + p] * h + Q[c * BH + p];
  }
}

__global__ void scan_c_kernel(const b16* __restrict__ dl, const b16* __restrict__ uu,
                              const float* __restrict__ Hs, b16* __restrict__ hsel) {
  int g = blockIdx.x * 256 + threadIdx.x;
  int c = g >> 15;
  int p = g & (BH - 1);
  const b16* dp = dl + (size_t)c * CS * BH + p;
  const b16* up = uu + (size_t)c * CS * BH + p;
  b16* hp = hsel + (size_t)(c * (CS / 2)) * BH + p;
  float h = Hs[g];
#pragma unroll 4
  for (int s = 0; s < CS; ++s) {
    float d = (float)dp[(size_t)s * BH];
    float u = (float)up[(size_t)s * BH];
    h = (1.f - d) * h + d * u;
    if (s & 1) hp[(size_t)(s >> 1) * BH] = (b16)h;
  }
}

// ---------------------------------------------------------------------------
extern "C" void kernel_launch(void* const* d_in, const int* in_sizes, int n_in,
                              void* d_out, int out_size, void* d_ws, size_t ws_size,
                              hipStream_t stream) {
  const float* x   = (const float*)d_in[0];
  // d_in[1] = A (unused by the reference forward)
  const float* WB  = (const float*)d_in[2];
  const float* Wc  = (const float*)d_in[3];
  const float* Wd  = (const float*)d_in[4];
  const float* bd  = (const float*)d_in[5];
  const float* Win = (const float*)d_in[6];
  const float* bi  = (const float*)d_in[7];
  const float* Wcp = (const float*)d_in[8];
  const float* bc  = (const float*)d_in[9];
  float* out = (float*)d_out;

  char* w = (char*)d_ws;
  size_t off = 0;
  auto alloc = [&](size_t bytes) {
    void* p = w + off;
    off += (bytes + 255) & ~(size_t)255;
    return p;
  };
  b16* xb   = (b16*)alloc((size_t)S_LEN * BATCH * D_INP * 2);  // 64 MB
  b16* Wdu  = (b16*)alloc((size_t)2 * H_DIM * D_INP * 2);      // 8 MB
  b16* Wcb  = (b16*)alloc((size_t)H_DIM * D_INP * 2);          // 4 MB
  b16* Wcpb = (b16*)alloc((size_t)D_INP * H_DIM * 2);          // 4 MB
  b16* dbuf = (b16*)alloc((size_t)S_LEN * BH * 2);             // 128 MB
  b16* ubuf = (b16*)alloc((size_t)S_LEN * BH * 2);             // 128 MB
  b16* hsel = (b16*)alloc((size_t)SC * BH * 2);                // 64 MB
  b16* ysel = (b16*)alloc((size_t)SC * BH * 2);                // 64 MB
  float* P  = (float*)alloc((size_t)NC * BH * 4);              // 2 MB
  float* Q  = (float*)alloc((size_t)NC * BH * 4);              // 2 MB
  float* Hs = (float*)alloc((size_t)NC * BH * 4);              // 2 MB
  if (off > ws_size) {
    fprintf(stderr, "kernel_launch: ws too small: need %zu have %zu\n", off, ws_size);
    return;  // fail visibly (output stays zero) rather than corrupt memory
  }

  // 1) x -> bf16
  int n4 = S_LEN * BATCH * D_INP / 4;
  cvt_x_kernel<<<(n4 + 255) / 256, 256, 0, stream>>>(x, xb, n4);
  // 2) weights -> bf16 (+ W_in+W_B fold)
  int hd4 = H_DIM * D_INP / 4;
  prep_w_kernel<<<(hd4 + 255) / 256, 256, 0, stream>>>(Wd, Win, WB, Wc, Wcp, Wdu, Wcb, Wcpb);
  // 3) delta/u projections: M=32768, N=4096, K=1024
  dim3 g1(2 * H_DIM / 128, S_LEN * BATCH / 128);
  gemm_bt<0><<<g1, 256, 0, stream>>>(xb, Wdu, D_INP, bd, bi, nullptr, dbuf, ubuf, nullptr);
  // 4-6) chunked scan over S
  scan_a_kernel<<<NC * BH / 256, 256, 0, stream>>>(dbuf, ubuf, P, Q);
  scan_b_kernel<<<BH / 256, 256, 0, stream>>>(P, Q, Hs);
  scan_c_kernel<<<NC * BH / 256, 256, 0, stream>>>(dbuf, ubuf, Hs, hsel);
  // 7) C projection at odd timesteps, fused *h: M=16384, N=2048, K=1024
  dim3 g2(H_DIM / 128, SC * BATCH / 128);
  gemm_bt<1><<<g2, 256, 0, stream>>>(xb, Wcb, D_INP, nullptr, nullptr, hsel, ysel, nullptr, nullptr);
  // 8) compress: M=16384, N=1024, K=2048, fp32 out + b_comp
  dim3 g3(D_INP / 128, SC * BATCH / 128);
  gemm_bt<2><<<g3, 256, 0, stream>>>(ysel, Wcpb, H_DIM, bc, nullptr, nullptr, nullptr, nullptr, out);
}

// Round 2
// 1155.587 us; speedup vs baseline: 1.0400x; 1.0400x over previous
//
#include <hip/hip_runtime.h>
#include <hip/hip_bf16.h>
#include <cstdio>

// Problem constants (S6HistoryCompressor)
#define S_LEN 2048
#define BATCH 16
#define D_INP 1024
#define H_DIM 2048
#define SC    (S_LEN / 2)       // compressed length (step=2, rows 1,3,...,2047)
#define BH    (BATCH * H_DIM)   // 32768 independent recurrences
#define NC    16                // scan chunks
#define CS    (S_LEN / NC)      // 128 steps per chunk

typedef __bf16 b16;
typedef __bf16 b16x8 __attribute__((ext_vector_type(8)));
typedef __bf16 b16x4 __attribute__((ext_vector_type(4)));
typedef float  f32x4 __attribute__((ext_vector_type(4)));

// XOR swizzle for LDS tile [128 rows][32 bf16 cols], 16B granules.
// Physical slot p in row r holds LOGICAL granule p ^ ((r>>1)&3).
// Frag reads below hit 2-way (free) bank aliasing only.
__device__ __forceinline__ int sw_off(int r, int k8) {
  return r * 32 + ((k8 ^ ((r >> 1) & 3)) << 3);
}

// Async global -> LDS, 16 B per lane. LDS dest = wave-uniform base + lane*16
// (hardware rule, m104/m108); swizzle is applied on the GLOBAL address side.
__device__ __forceinline__ void gl2lds16(const b16* g, b16* l) {
  __builtin_amdgcn_global_load_lds(
      (const __attribute__((address_space(1))) void*)g,
      (__attribute__((address_space(3))) void*)l, 16, 0, 0);
}

// ---------------------------------------------------------------------------
// Conversions
// ---------------------------------------------------------------------------
__global__ void cvt_x_kernel(const float* __restrict__ in, b16* __restrict__ out, int n4) {
  int i = blockIdx.x * 256 + threadIdx.x;
  if (i >= n4) return;
  float4 v = ((const float4*)in)[i];
  b16x4 o = {(b16)v.x, (b16)v.y, (b16)v.z, (b16)v.w};
  ((b16x4*)out)[i] = o;
}

// Build Wdu = [W_delta ; W_in + W_B] (bf16), plus bf16 copies of W_C, W_comp.
__global__ void prep_w_kernel(const float* __restrict__ Wd, const float* __restrict__ Win,
                              const float* __restrict__ WB, const float* __restrict__ Wc,
                              const float* __restrict__ Wcp,
                              b16* __restrict__ Wdu, b16* __restrict__ Wcb,
                              b16* __restrict__ Wcpb) {
  const int HD4 = (H_DIM * D_INP) / 4;
  int i = blockIdx.x * 256 + threadIdx.x;
  if (i >= HD4) return;
  float4 a = ((const float4*)Wd)[i];
  float4 b = ((const float4*)Win)[i];
  float4 c = ((const float4*)WB)[i];
  float4 d = ((const float4*)Wc)[i];
  float4 e = ((const float4*)Wcp)[i];
  ((b16x4*)Wdu)[i] = {(b16)a.x, (b16)a.y, (b16)a.z, (b16)a.w};
  ((b16x4*)Wdu)[HD4 + i] = {(b16)(b.x + c.x), (b16)(b.y + c.y), (b16)(b.z + c.z), (b16)(b.w + c.w)};
  ((b16x4*)Wcb)[i] = {(b16)d.x, (b16)d.y, (b16)d.z, (b16)d.w};
  ((b16x4*)Wcpb)[i] = {(b16)e.x, (b16)e.y, (b16)e.z, (b16)e.w};
}

// ---------------------------------------------------------------------------
// GEMM: C[M,N] = A[M,K] (bf16 row-major) x W[N,K]^T (bf16 row-major, i.e. B^T)
// 128x128 block tile, 4 waves, each wave 64x64 via 4x4 grid of 16x16x32 MFMA.
// Staging via global_load_lds width=16 (m97 pattern): each wave DMAs 16 rows
// per call; lane i covers row wave*16+(i>>2), physical granule i&3, and loads
// the XOR-swizzled logical granule so the ds_read side stays conflict-free.
// MODE 0: N=2*H. n<H: delta=softplus(acc+b_delta[n]) -> ob0; else u=acc+b_in -> ob1.
// MODE 1: A rows remapped to odd timesteps of x; out = acc * hsel -> ob0 (y_sel).
// MODE 2: out fp32 = acc + bias0[n] -> of (final output).
// ---------------------------------------------------------------------------
template <int MODE>
__global__ __launch_bounds__(256, 2) void gemm_bt(
    const b16* __restrict__ A, const b16* __restrict__ W, int K,
    const float* __restrict__ bias0, const float* __restrict__ bias1,
    const b16* __restrict__ hsel, b16* __restrict__ ob0, b16* __restrict__ ob1,
    float* __restrict__ of) {
  __shared__ b16 As[128 * 32];
  __shared__ b16 Bs[128 * 32];
  const int tid  = threadIdx.x;
  const int lane = tid & 63;
  const int wave = tid >> 6;
  const int wr = wave >> 1, wc = wave & 1;
  const int m0 = blockIdx.y * 128;
  const int n0 = blockIdx.x * 128;
  const int lm = lane & 15;
  const int l8 = lane >> 4;
  // DMA staging decomposition: wave covers rows [wave*16, wave*16+16) (+64 for
  // second half); 4 lanes per row, 16B each.
  const int rL  = wave * 16 + (lane >> 2);  // local row, first half
  const int k8p = lane & 3;                 // physical 16B granule

  f32x4 acc[4][4];
#pragma unroll
  for (int i = 0; i < 4; i++)
#pragma unroll
    for (int j = 0; j < 4; j++) acc[i][j] = (f32x4)0.f;

  for (int k0 = 0; k0 < K; k0 += 32) {
#pragma unroll
    for (int hh = 0; hh < 2; ++hh) {
      const int r = rL + hh * 64;                   // LDS row 0..127
      const int k8l = k8p ^ ((r >> 1) & 3);         // logical granule to fetch
      b16* ldsA = As + (wave * 16 + hh * 64) * 32;  // wave-uniform base
      b16* ldsB = Bs + (wave * 16 + hh * 64) * 32;
      long arow = m0 + r;
      if (MODE == 1) arow = 2 * arow - (arow & 15) + 16;  // odd-timestep remap
      gl2lds16(A + arow * (long)K + k0 + k8l * 8, ldsA);
      gl2lds16(W + (long)(n0 + r) * K + k0 + k8l * 8, ldsB);
    }
    __syncthreads();
    b16x8 af[4], bfr[4];
#pragma unroll
    for (int i = 0; i < 4; i++) af[i] = *(const b16x8*)(As + sw_off(wr * 64 + i * 16 + lm, l8));
#pragma unroll
    for (int j = 0; j < 4; j++) bfr[j] = *(const b16x8*)(Bs + sw_off(wc * 64 + j * 16 + lm, l8));
#pragma unroll
    for (int i = 0; i < 4; i++)
#pragma unroll
      for (int j = 0; j < 4; j++)
        acc[i][j] = __builtin_amdgcn_mfma_f32_16x16x32_bf16(af[i], bfr[j], acc[i][j], 0, 0, 0);
    __syncthreads();
  }

  // Epilogue. C/D layout: col = lane&15, row = (lane>>4)*4 + reg [m89/m91 verified].
#pragma unroll
  for (int i = 0; i < 4; i++) {
#pragma unroll
    for (int j = 0; j < 4; j++) {
      int n = n0 + wc * 64 + j * 16 + lm;
      int mb = m0 + wr * 64 + i * 16 + l8 * 4;
#pragma unroll
      for (int rg = 0; rg < 4; ++rg) {
        float v = acc[i][j][rg];
        long m = mb + rg;
        if (MODE == 0) {
          if (n < H_DIM) {
            float t = v + bias0[n];
            float sp = (t > 15.f) ? t : log1pf(expf(t));
            ob0[m * H_DIM + n] = (b16)sp;
          } else {
            ob1[m * H_DIM + (n - H_DIM)] = (b16)(v + bias1[n - H_DIM]);
          }
        } else if (MODE == 1) {
          float hv = (float)hsel[m * H_DIM + n];
          ob0[m * H_DIM + n] = (b16)(v * hv);
        } else {
          of[m * D_INP + n] = v + bias0[n];
        }
      }
    }
  }
}

// ---------------------------------------------------------------------------
// Chunked-scan recurrence: h_t = (1-d_t) h_{t-1} + d_t u_t  (elementwise in B*H)
// ---------------------------------------------------------------------------
__global__ void scan_a_kernel(const b16* __restrict__ dl, const b16* __restrict__ uu,
                              float* __restrict__ P, float* __restrict__ Q) {
  int g = blockIdx.x * 256 + threadIdx.x;  // [0, NC*BH)
  int c = g >> 15;                          // chunk
  int p = g & (BH - 1);                     // (b,h) flat
  const b16* dp = dl + (size_t)c * CS * BH + p;
  const b16* up = uu + (size_t)c * CS * BH + p;
  float h = 0.f, pr = 1.f;
#pragma unroll 4
  for (int s = 0; s < CS; ++s) {
    float d = (float)dp[(size_t)s * BH];
    float u = (float)up[(size_t)s * BH];
    float a = 1.f - d;
    h = a * h + d * u;
    pr *= a;
  }
  P[g] = pr;
  Q[g] = h;
}

__global__ void scan_b_kernel(const float* __restrict__ P, const float* __restrict__ Q,
                              float* __restrict__ Hs) {
  int p = blockIdx.x * 256 + threadIdx.x;  // [0, BH)
  float h = 0.f;
#pragma unroll
  for (int c = 0; c < NC; ++c) {
    Hs[c * BH + p] = h;
    h = P[c * BH + p] * h + Q[c * BH + p];
  }
}

__global__ void scan_c_kernel(const b16* __restrict__ dl, const b16* __restrict__ uu,
                              const float* __restrict__ Hs, b16* __restrict__ hsel) {
  int g = blockIdx.x * 256 + threadIdx.x;
  int c = g >> 15;
  int p = g & (BH - 1);
  const b16* dp = dl + (size_t)c * CS * BH + p;
  const b16* up = uu + (size_t)c * CS * BH + p;
  b16* hp = hsel + (size_t)(c * (CS / 2)) * BH + p;
  float h = Hs[g];
#pragma unroll 4
  for (int s = 0; s < CS; ++s) {
    float d = (float)dp[(size_t)s * BH];
    float u = (float)up[(size_t)s * BH];
    h = (1.f - d) * h + d * u;
    if (s & 1) hp[(size_t)(s >> 1) * BH] = (b16)h;
  }
}

// ---------------------------------------------------------------------------
extern "C" void kernel_launch(void* const* d_in, const int* in_sizes, int n_in,
                              void* d_out, int out_size, void* d_ws, size_t ws_size,
                              hipStream_t stream) {
  const float* x   = (const float*)d_in[0];
  // d_in[1] = A (unused by the reference forward)
  const float* WB  = (const float*)d_in[2];
  const float* Wc  = (const float*)d_in[3];
  const float* Wd  = (const float*)d_in[4];
  const float* bd  = (const float*)d_in[5];
  const float* Win = (const float*)d_in[6];
  const float* bi  = (const float*)d_in[7];
  const float* Wcp = (const float*)d_in[8];
  const float* bc  = (const float*)d_in[9];
  float* out = (float*)d_out;

  char* w = (char*)d_ws;
  size_t off = 0;
  auto alloc = [&](size_t bytes) {
    void* p = w + off;
    off += (bytes + 255) & ~(size_t)255;
    return p;
  };
  b16* xb   = (b16*)alloc((size_t)S_LEN * BATCH * D_INP * 2);  // 64 MB
  b16* Wdu  = (b16*)alloc((size_t)2 * H_DIM * D_INP * 2);      // 8 MB
  b16* Wcb  = (b16*)alloc((size_t)H_DIM * D_INP * 2);          // 4 MB
  b16* Wcpb = (b16*)alloc((size_t)D_INP * H_DIM * 2);          // 4 MB
  b16* dbuf = (b16*)alloc((size_t)S_LEN * BH * 2);             // 128 MB
  b16* ubuf = (b16*)alloc((size_t)S_LEN * BH * 2);             // 128 MB
  b16* hsel = (b16*)alloc((size_t)SC * BH * 2);                // 64 MB
  b16* ysel = (b16*)alloc((size_t)SC * BH * 2);                // 64 MB
  float* P  = (float*)alloc((size_t)NC * BH * 4);              // 2 MB
  float* Q  = (float*)alloc((size_t)NC * BH * 4);              // 2 MB
  float* Hs = (float*)alloc((size_t)NC * BH * 4);              // 2 MB
  if (off > ws_size) {
    fprintf(stderr, "kernel_launch: ws too small: need %zu have %zu\n", off, ws_size);
    return;  // fail visibly (output stays zero) rather than corrupt memory
  }

  // 1) x -> bf16
  int n4 = S_LEN * BATCH * D_INP / 4;
  cvt_x_kernel<<<(n4 + 255) / 256, 256, 0, stream>>>(x, xb, n4);
  // 2) weights -> bf16 (+ W_in+W_B fold)
  int hd4 = H_DIM * D_INP / 4;
  prep_w_kernel<<<(hd4 + 255) / 256, 256, 0, stream>>>(Wd, Win, WB, Wc, Wcp, Wdu, Wcb, Wcpb);
  // 3) delta/u projections: M=32768, N=4096, K=1024
  dim3 g1(2 * H_DIM / 128, S_LEN * BATCH / 128);
  gemm_bt<0><<<g1, 256, 0, stream>>>(xb, Wdu, D_INP, bd, bi, nullptr, dbuf, ubuf, nullptr);
  // 4-6) chunked scan over S
  scan_a_kernel<<<NC * BH / 256, 256, 0, stream>>>(dbuf, ubuf, P, Q);
  scan_b_kernel<<<BH / 256, 256, 0, stream>>>(P, Q, Hs);
  scan_c_kernel<<<NC * BH / 256, 256, 0, stream>>>(dbuf, ubuf, Hs, hsel);
  // 7) C projection at odd timesteps, fused *h: M=16384, N=2048, K=1024
  dim3 g2(H_DIM / 128, SC * BATCH / 128);
  gemm_bt<1><<<g2, 256, 0, stream>>>(xb, Wcb, D_INP, nullptr, nullptr, hsel, ysel, nullptr, nullptr);
  // 8) compress: M=16384, N=1024, K=2048, fp32 out + b_comp
  dim3 g3(D_INP / 128, SC * BATCH / 128);
  gemm_bt<2><<<g3, 256, 0, stream>>>(ysel, Wcpb, H_DIM, bc, nullptr, nullptr, nullptr, nullptr, out);
}

// Round 3
// 873.767 us; speedup vs baseline: 1.3755x; 1.3225x over previous
//
#include <hip/hip_runtime.h>
#include <hip/hip_bf16.h>
#include <cstdio>

// Problem constants (S6HistoryCompressor)
#define S_LEN 2048
#define BATCH 16
#define D_INP 1024
#define H_DIM 2048
#define SC    (S_LEN / 2)       // compressed length (step=2, rows 1,3,...,2047)
#define BH    (BATCH * H_DIM)   // 32768 independent recurrences
#define NC    16                // scan chunks
#define CS    (S_LEN / NC)      // 128 steps per chunk

typedef __bf16 b16;
typedef __bf16 b16x8 __attribute__((ext_vector_type(8)));
typedef __bf16 b16x4 __attribute__((ext_vector_type(4)));
typedef float  f32x4 __attribute__((ext_vector_type(4)));

// XOR swizzle for LDS tile [128 rows][32 bf16 cols], 16B granules.
// Physical slot p in row r holds LOGICAL granule p ^ ((r>>1)&3).
// Frag reads below hit 2-way (free) bank aliasing only.
__device__ __forceinline__ int sw_off(int r, int k8) {
  return r * 32 + ((k8 ^ ((r >> 1) & 3)) << 3);
}

// Async global -> LDS, 16 B per lane. LDS dest = wave-uniform base + lane*16
// (hardware rule, m104/m108); swizzle is applied on the GLOBAL address side.
__device__ __forceinline__ void gl2lds16(const b16* g, b16* l) {
  __builtin_amdgcn_global_load_lds(
      (const __attribute__((address_space(1))) void*)g,
      (__attribute__((address_space(3))) void*)l, 16, 0, 0);
}

// Fast branchless softplus: log(1+e^t) = max(t,0) + log(1+e^-|t|).
// v_exp_f32/v_log_f32 via __expf/__logf; ~1e-7 rel err, fine for bf16 out.
__device__ __forceinline__ float softplus_fast(float t) {
  float e = __expf(-fabsf(t));
  return fmaxf(t, 0.f) + __logf(1.f + e);
}

// ---------------------------------------------------------------------------
// Conversions
// ---------------------------------------------------------------------------
__global__ void cvt_x_kernel(const float* __restrict__ in, b16* __restrict__ out, int n4) {
  int i = blockIdx.x * 256 + threadIdx.x;
  if (i >= n4) return;
  float4 v = ((const float4*)in)[i];
  b16x4 o = {(b16)v.x, (b16)v.y, (b16)v.z, (b16)v.w};
  ((b16x4*)out)[i] = o;
}

// Build Wdu = [W_delta ; W_in + W_B] (bf16), plus bf16 copies of W_C, W_comp.
__global__ void prep_w_kernel(const float* __restrict__ Wd, const float* __restrict__ Win,
                              const float* __restrict__ WB, const float* __restrict__ Wc,
                              const float* __restrict__ Wcp,
                              b16* __restrict__ Wdu, b16* __restrict__ Wcb,
                              b16* __restrict__ Wcpb) {
  const int HD4 = (H_DIM * D_INP) / 4;
  int i = blockIdx.x * 256 + threadIdx.x;
  if (i >= HD4) return;
  float4 a = ((const float4*)Wd)[i];
  float4 b = ((const float4*)Win)[i];
  float4 c = ((const float4*)WB)[i];
  float4 d = ((const float4*)Wc)[i];
  float4 e = ((const float4*)Wcp)[i];
  ((b16x4*)Wdu)[i] = {(b16)a.x, (b16)a.y, (b16)a.z, (b16)a.w};
  ((b16x4*)Wdu)[HD4 + i] = {(b16)(b.x + c.x), (b16)(b.y + c.y), (b16)(b.z + c.z), (b16)(b.w + c.w)};
  ((b16x4*)Wcb)[i] = {(b16)d.x, (b16)d.y, (b16)d.z, (b16)d.w};
  ((b16x4*)Wcpb)[i] = {(b16)e.x, (b16)e.y, (b16)e.z, (b16)e.w};
}

// ---------------------------------------------------------------------------
// GEMM: C[M,N] = A[M,K] (bf16 row-major) x W[N,K]^T (bf16 row-major, i.e. B^T)
// 128x128 block tile, 4 waves, each wave 64x64 via 4x4 grid of 16x16x32 MFMA.
// Staging via global_load_lds width=16 (m97 pattern).
// MODE 0: N=2*H, block-uniform split: n0<H -> delta=softplus(acc+b_delta);
//         else u=acc+b_in. Epilogue branch hoisted to block level.
// MODE 1: A rows remapped to odd timesteps of x; out = acc * hsel -> ob0 (y_sel).
// MODE 2: out fp32 = acc + bias0[n] -> of (final output).
// ---------------------------------------------------------------------------
template <int MODE>
__global__ __launch_bounds__(256, 2) void gemm_bt(
    const b16* __restrict__ A, const b16* __restrict__ W, int K,
    const float* __restrict__ bias0, const float* __restrict__ bias1,
    const b16* __restrict__ hsel, b16* __restrict__ ob0, b16* __restrict__ ob1,
    float* __restrict__ of) {
  __shared__ b16 As[128 * 32];
  __shared__ b16 Bs[128 * 32];
  const int tid  = threadIdx.x;
  const int lane = tid & 63;
  const int wave = tid >> 6;
  const int wr = wave >> 1, wc = wave & 1;
  const int m0 = blockIdx.y * 128;
  const int n0 = blockIdx.x * 128;
  const int lm = lane & 15;
  const int l8 = lane >> 4;
  // DMA staging decomposition: wave covers rows [wave*16, wave*16+16) (+64 for
  // second half); 4 lanes per row, 16B each.
  const int rL  = wave * 16 + (lane >> 2);  // local row, first half
  const int k8p = lane & 3;                 // physical 16B granule

  f32x4 acc[4][4];
#pragma unroll
  for (int i = 0; i < 4; i++)
#pragma unroll
    for (int j = 0; j < 4; j++) acc[i][j] = (f32x4)0.f;

  for (int k0 = 0; k0 < K; k0 += 32) {
#pragma unroll
    for (int hh = 0; hh < 2; ++hh) {
      const int r = rL + hh * 64;                   // LDS row 0..127
      const int k8l = k8p ^ ((r >> 1) & 3);         // logical granule to fetch
      b16* ldsA = As + (wave * 16 + hh * 64) * 32;  // wave-uniform base
      b16* ldsB = Bs + (wave * 16 + hh * 64) * 32;
      long arow = m0 + r;
      if (MODE == 1) arow = 2 * arow - (arow & 15) + 16;  // odd-timestep remap
      gl2lds16(A + arow * (long)K + k0 + k8l * 8, ldsA);
      gl2lds16(W + (long)(n0 + r) * K + k0 + k8l * 8, ldsB);
    }
    __syncthreads();
    b16x8 af[4], bfr[4];
#pragma unroll
    for (int i = 0; i < 4; i++) af[i] = *(const b16x8*)(As + sw_off(wr * 64 + i * 16 + lm, l8));
#pragma unroll
    for (int j = 0; j < 4; j++) bfr[j] = *(const b16x8*)(Bs + sw_off(wc * 64 + j * 16 + lm, l8));
#pragma unroll
    for (int i = 0; i < 4; i++)
#pragma unroll
      for (int j = 0; j < 4; j++)
        acc[i][j] = __builtin_amdgcn_mfma_f32_16x16x32_bf16(af[i], bfr[j], acc[i][j], 0, 0, 0);
    __syncthreads();
  }

  // Epilogue. C/D layout: col = lane&15, row = (lane>>4)*4 + reg [m89/m91].
  // Base pointers precomputed per i; inner stores are base + const*ld offsets.
  if (MODE == 0) {
    const bool is_delta = (n0 < H_DIM);               // block-uniform
    const float* bias = is_delta ? bias0 : bias1;
    b16* ob = is_delta ? ob0 : ob1;
    const int nc0 = (n0 & (H_DIM - 1)) + wc * 64 + lm;
    float bv[4];
#pragma unroll
    for (int j = 0; j < 4; j++) bv[j] = bias[nc0 + j * 16];
#pragma unroll
    for (int i = 0; i < 4; i++) {
      const long rb = m0 + wr * 64 + i * 16 + l8 * 4;
      b16* pr = ob + rb * H_DIM + nc0;
      if (is_delta) {
#pragma unroll
        for (int j = 0; j < 4; j++)
#pragma unroll
          for (int rg = 0; rg < 4; ++rg)
            pr[(long)rg * H_DIM + j * 16] = (b16)softplus_fast(acc[i][j][rg] + bv[j]);
      } else {
#pragma unroll
        for (int j = 0; j < 4; j++)
#pragma unroll
          for (int rg = 0; rg < 4; ++rg)
            pr[(long)rg * H_DIM + j * 16] = (b16)(acc[i][j][rg] + bv[j]);
      }
    }
  } else if (MODE == 1) {
    const int nc0 = n0 + wc * 64 + lm;
#pragma unroll
    for (int i = 0; i < 4; i++) {
      const long rb = m0 + wr * 64 + i * 16 + l8 * 4;
      const b16* hp = hsel + rb * H_DIM + nc0;
      b16* pr = ob0 + rb * H_DIM + nc0;
#pragma unroll
      for (int j = 0; j < 4; j++)
#pragma unroll
        for (int rg = 0; rg < 4; ++rg) {
          float hv = (float)hp[(long)rg * H_DIM + j * 16];
          pr[(long)rg * H_DIM + j * 16] = (b16)(acc[i][j][rg] * hv);
        }
    }
  } else {
    const int nc0 = n0 + wc * 64 + lm;
    float bv[4];
#pragma unroll
    for (int j = 0; j < 4; j++) bv[j] = bias0[nc0 + j * 16];
#pragma unroll
    for (int i = 0; i < 4; i++) {
      const long rb = m0 + wr * 64 + i * 16 + l8 * 4;
      float* pr = of + rb * D_INP + nc0;
#pragma unroll
      for (int j = 0; j < 4; j++)
#pragma unroll
        for (int rg = 0; rg < 4; ++rg)
          pr[(long)rg * D_INP + j * 16] = acc[i][j][rg] + bv[j];
    }
  }
}

// ---------------------------------------------------------------------------
// Chunked-scan recurrence: h_t = (1-d_t) h_{t-1} + d_t u_t  (elementwise in B*H)
// ---------------------------------------------------------------------------
__global__ void scan_a_kernel(const b16* __restrict__ dl, const b16* __restrict__ uu,
                              float* __restrict__ P, float* __restrict__ Q) {
  int g = blockIdx.x * 256 + threadIdx.x;  // [0, NC*BH)
  int c = g >> 15;                          // chunk
  int p = g & (BH - 1);                     // (b,h) flat
  const b16* dp = dl + (size_t)c * CS * BH + p;
  const b16* up = uu + (size_t)c * CS * BH + p;
  float h = 0.f, pr = 1.f;
#pragma unroll 4
  for (int s = 0; s < CS; ++s) {
    float d = (float)dp[(size_t)s * BH];
    float u = (float)up[(size_t)s * BH];
    float a = 1.f - d;
    h = a * h + d * u;
    pr *= a;
  }
  P[g] = pr;
  Q[g] = h;
}

__global__ void scan_b_kernel(const float* __restrict__ P, const float* __restrict__ Q,
                              float* __restrict__ Hs) {
  int p = blockIdx.x * 256 + threadIdx.x;  // [0, BH)
  float h = 0.f;
#pragma unroll
  for (int c = 0; c < NC; ++c) {
    Hs[c * BH + p] = h;
    h = P[c * BH + p] * h + Q[c * BH + p];
  }
}

__global__ void scan_c_kernel(const b16* __restrict__ dl, const b16* __restrict__ uu,
                              const float* __restrict__ Hs, b16* __restrict__ hsel) {
  int g = blockIdx.x * 256 + threadIdx.x;
  int c = g >> 15;
  int p = g & (BH - 1);
  const b16* dp = dl + (size_t)c * CS * BH + p;
  const b16* up = uu + (size_t)c * CS * BH + p;
  b16* hp = hsel + (size_t)(c * (CS / 2)) * BH + p;
  float h = Hs[g];
#pragma unroll 4
  for (int s = 0; s < CS; ++s) {
    float d = (float)dp[(size_t)s * BH];
    float u = (float)up[(size_t)s * BH];
    h = (1.f - d) * h + d * u;
    if (s & 1) hp[(size_t)(s >> 1) * BH] = (b16)h;
  }
}

// ---------------------------------------------------------------------------
extern "C" void kernel_launch(void* const* d_in, const int* in_sizes, int n_in,
                              void* d_out, int out_size, void* d_ws, size_t ws_size,
                              hipStream_t stream) {
  const float* x   = (const float*)d_in[0];
  // d_in[1] = A (unused by the reference forward)
  const float* WB  = (const float*)d_in[2];
  const float* Wc  = (const float*)d_in[3];
  const float* Wd  = (const float*)d_in[4];
  const float* bd  = (const float*)d_in[5];
  const float* Win = (const float*)d_in[6];
  const float* bi  = (const float*)d_in[7];
  const float* Wcp = (const float*)d_in[8];
  const float* bc  = (const float*)d_in[9];
  float* out = (float*)d_out;

  char* w = (char*)d_ws;
  size_t off = 0;
  auto alloc = [&](size_t bytes) {
    void* p = w + off;
    off += (bytes + 255) & ~(size_t)255;
    return p;
  };
  b16* xb   = (b16*)alloc((size_t)S_LEN * BATCH * D_INP * 2);  // 64 MB
  b16* Wdu  = (b16*)alloc((size_t)2 * H_DIM * D_INP * 2);      // 8 MB
  b16* Wcb  = (b16*)alloc((size_t)H_DIM * D_INP * 2);          // 4 MB
  b16* Wcpb = (b16*)alloc((size_t)D_INP * H_DIM * 2);          // 4 MB
  b16* dbuf = (b16*)alloc((size_t)S_LEN * BH * 2);             // 128 MB
  b16* ubuf = (b16*)alloc((size_t)S_LEN * BH * 2);             // 128 MB
  b16* hsel = (b16*)alloc((size_t)SC * BH * 2);                // 64 MB
  b16* ysel = (b16*)alloc((size_t)SC * BH * 2);                // 64 MB
  float* P  = (float*)alloc((size_t)NC * BH * 4);              // 2 MB
  float* Q  = (float*)alloc((size_t)NC * BH * 4);              // 2 MB
  float* Hs = (float*)alloc((size_t)NC * BH * 4);              // 2 MB
  if (off > ws_size) {
    fprintf(stderr, "kernel_launch: ws too small: need %zu have %zu\n", off, ws_size);
    return;  // fail visibly (output stays zero) rather than corrupt memory
  }

  // 1) x -> bf16
  int n4 = S_LEN * BATCH * D_INP / 4;
  cvt_x_kernel<<<(n4 + 255) / 256, 256, 0, stream>>>(x, xb, n4);
  // 2) weights -> bf16 (+ W_in+W_B fold)
  int hd4 = H_DIM * D_INP / 4;
  prep_w_kernel<<<(hd4 + 255) / 256, 256, 0, stream>>>(Wd, Win, WB, Wc, Wcp, Wdu, Wcb, Wcpb);
  // 3) delta/u projections: M=32768, N=4096, K=1024
  dim3 g1(2 * H_DIM / 128, S_LEN * BATCH / 128);
  gemm_bt<0><<<g1, 256, 0, stream>>>(xb, Wdu, D_INP, bd, bi, nullptr, dbuf, ubuf, nullptr);
  // 4-6) chunked scan over S
  scan_a_kernel<<<NC * BH / 256, 256, 0, stream>>>(dbuf, ubuf, P, Q);
  scan_b_kernel<<<BH / 256, 256, 0, stream>>>(P, Q, Hs);
  scan_c_kernel<<<NC * BH / 256, 256, 0, stream>>>(dbuf, ubuf, Hs, hsel);
  // 7) C projection at odd timesteps, fused *h: M=16384, N=2048, K=1024
  dim3 g2(H_DIM / 128, SC * BATCH / 128);
  gemm_bt<1><<<g2, 256, 0, stream>>>(xb, Wcb, D_INP, nullptr, nullptr, hsel, ysel, nullptr, nullptr);
  // 8) compress: M=16384, N=1024, K=2048, fp32 out + b_comp
  dim3 g3(D_INP / 128, SC * BATCH / 128);
  gemm_bt<2><<<g3, 256, 0, stream>>>(ysel, Wcpb, H_DIM, bc, nullptr, nullptr, nullptr, nullptr, out);
}